// Round 1
// baseline (1549.618 us; speedup 1.0000x reference)
//
#include <hip/hip_runtime.h>
#include <cstdint>

#define FDIM 64
#define KNN 32
#define MAXCAP 2048
#define NBUCKET 256

typedef unsigned int u32;
typedef unsigned long long u64;

// ---- query load + dot helpers: shared between k_hist and k_filter so d2 is
// ---- computed with a bitwise-identical FMA DAG in both (threshold guarantee).
__device__ __forceinline__ float load_query(const float* __restrict__ x, int q, float4* xv) {
    const float4* xp = (const float4*)(x + (size_t)q * FDIM);
    float n0 = 0.f, n1 = 0.f, n2 = 0.f, n3 = 0.f;
#pragma unroll
    for (int k = 0; k < 16; ++k) {
        float4 v = xp[k];
        xv[k] = v;
        n0 = fmaf(v.x, v.x, n0);
        n1 = fmaf(v.y, v.y, n1);
        n2 = fmaf(v.z, v.z, n2);
        n3 = fmaf(v.w, v.w, n3);
    }
    return (n0 + n1) + (n2 + n3);
}

__device__ __forceinline__ float dot_row(const float4* __restrict__ xv, const float* __restrict__ row) {
    const float4* rv = (const float4*)row;
    float d0 = 0.f, d1 = 0.f, d2 = 0.f, d3 = 0.f;
#pragma unroll
    for (int k = 0; k < 16; ++k) {
        float4 r = rv[k];
        float4 a = xv[k];
        d0 = fmaf(a.x, r.x, d0);
        d1 = fmaf(a.y, r.y, d1);
        d2 = fmaf(a.z, r.z, d2);
        d3 = fmaf(a.w, r.w, d3);
    }
    return (d0 + d1) + (d2 + d3);
}

// ---- K1: row norms of X_data
__global__ __launch_bounds__(256) void k_xnorm(const float* __restrict__ X, float* __restrict__ Xn, int N) {
    int i = blockIdx.x * 256 + threadIdx.x;
    if (i >= N) return;
    const float4* r = (const float4*)(X + (size_t)i * FDIM);
    float d0 = 0.f, d1 = 0.f, d2 = 0.f, d3 = 0.f;
#pragma unroll
    for (int k = 0; k < 16; ++k) {
        float4 v = r[k];
        d0 = fmaf(v.x, v.x, d0);
        d1 = fmaf(v.y, v.y, d1);
        d2 = fmaf(v.z, v.z, d2);
        d3 = fmaf(v.w, v.w, d3);
    }
    Xn[i] = (d0 + d1) + (d2 + d3);
}

// ---- K2: per-query histogram of d2 over a stride-16 sample of points.
// thread = query; per-thread 256-bucket u8 histogram in LDS column [b][t].
// u8 saturation is safe: any bucket fully below the 32nd sample value holds
// < 32 counts; saturation in/above the cutoff bucket only pushes T up (safe).
__global__ __launch_bounds__(256) void k_hist(const float* __restrict__ x, const float* __restrict__ X,
                                              const float* __restrict__ Xn, u32* __restrict__ hist,
                                              int N, int nsamp, int sj) {
    __shared__ unsigned char h8[NBUCKET * 256];
    int t = threadIdx.x;
    u32* h32 = (u32*)h8;
#pragma unroll
    for (int k = 0; k < 64; ++k) h32[k * 256 + t] = 0;
    __syncthreads();

    int q = blockIdx.x * 256 + t;
    float4 xv[16];
    float xn = load_query(x, q, xv);

    for (int j = 0; j < sj; ++j) {
        int s = blockIdx.y * sj + j;
        int p = s * 16;
        if (s < nsamp && p < N) {
            float dp = dot_row(xv, X + (size_t)p * FDIM);
            float d2 = fmaxf(xn + Xn[p] - 2.f * dp, 0.f);
            int b = min(NBUCKET - 1, (int)d2);
            int idx = b * 256 + t;
            unsigned char v = h8[idx];
            h8[idx] = (v == 255u) ? v : (unsigned char)(v + 1);
        }
    }
    __syncthreads();
    // flush own column: pack two u8 buckets per u32 atomic into u16-pair hist
#pragma unroll
    for (int w = 0; w < 128; ++w) {
        u32 v0 = h8[(2 * w) * 256 + t];
        u32 v1 = h8[(2 * w + 1) * 256 + t];
        if (v0 | v1) atomicAdd(&hist[(size_t)q * 128 + w], v0 | (v1 << 16));
    }
}

// ---- K2b: threshold = upper edge of first bucket with cumulative count >= 32
__global__ __launch_bounds__(256) void k_thresh(const u32* __restrict__ hist, float* __restrict__ Tq, int B) {
    int q = blockIdx.x * 256 + threadIdx.x;
    if (q >= B) return;
    const u32* h = hist + (size_t)q * 128;
    int cum = 0;
    float T = (float)NBUCKET;
    for (int w = 0; w < 128; ++w) {
        u32 v = h[w];
        cum += (int)(v & 0xffffu);
        if (cum >= KNN) { T = (float)(2 * w + 1); break; }
        cum += (int)(v >> 16);
        if (cum >= KNN) { T = (float)(2 * w + 2); break; }
    }
    Tq[q] = T;
}

// ---- K3: full pass; append candidates with d2 < T_q. thread = query, all
// threads walk the same point (broadcast row loads dedupe to one transaction).
__global__ __launch_bounds__(256) void k_filter(const float* __restrict__ x, const float* __restrict__ X,
                                                const float* __restrict__ Xn, const float* __restrict__ Tq,
                                                u32* __restrict__ cnt, u64* __restrict__ list,
                                                int N, int cap) {
    int t = threadIdx.x;
    int q = blockIdx.x * 256 + t;
    float4 xv[16];
    float xn = load_query(x, q, xv);
    float T = Tq[q];
    int base = blockIdx.y * 1024;
    int lim = min(1024, N - base);
    for (int j = 0; j < lim; ++j) {
        int p = base + j;
        float dp = dot_row(xv, X + (size_t)p * FDIM);
        float d2 = fmaxf(xn + Xn[p] - 2.f * dp, 0.f);
        if (d2 < T) {
            u32 slot = atomicAdd(&cnt[q], 1u);
            if (slot < (u32)cap)
                list[(size_t)q * cap + slot] = ((u64)__float_as_uint(d2) << 32) | (u32)p;
        }
    }
}

// ---- K4: exact top-32 of candidates (u64 key => tie-break on lower index,
// matching lax.top_k), then the gated-NN head. One block per query.
__global__ __launch_bounds__(256) void k_final(const float* __restrict__ x, const float* __restrict__ X,
                                               const float* __restrict__ y,
                                               const float* __restrict__ Wg, const float* __restrict__ bg,
                                               const float* __restrict__ W1, const float* __restrict__ b1,
                                               const float* __restrict__ Wl, const float* __restrict__ bl,
                                               const u32* __restrict__ cnt, const u64* __restrict__ list,
                                               float* __restrict__ out, int cap) {
    __shared__ u64 keys[MAXCAP];
    __shared__ u64 wk[4];
    __shared__ int wp[4];
    __shared__ u32 sel[KNN];
    __shared__ float gkc[KNN * 16];
    __shared__ float aggc[16];
    __shared__ float red[128];

    int t = threadIdx.x;
    int q = blockIdx.x;
    int m = (int)min(cnt[q], (u32)cap);

    for (int i = t; i < m; i += 256) keys[i] = list[(size_t)q * cap + i];
    __syncthreads();

    for (int r = 0; r < KNN; ++r) {
        u64 bk = ~0ull;
        int bp = -1;
        for (int i = t; i < m; i += 256) {
            u64 k = keys[i];
            if (k < bk) { bk = k; bp = i; }
        }
#pragma unroll
        for (int off = 32; off > 0; off >>= 1) {
            u64 ok = __shfl_down(bk, off);
            int op = __shfl_down(bp, off);
            if (ok < bk) { bk = ok; bp = op; }
        }
        if ((t & 63) == 0) { wk[t >> 6] = bk; wp[t >> 6] = bp; }
        __syncthreads();
        if (t == 0) {
            u64 fb = wk[0];
            int fp = wp[0];
            for (int w = 1; w < 4; ++w)
                if (wk[w] < fb) { fb = wk[w]; fp = wp[w]; }
            sel[r] = (u32)(fb & 0xffffffffu);
            if (fp >= 0) keys[fp] = ~0ull;
        }
        __syncthreads();
    }

    // gated = tanh(nf @ Wg + bg); 512 (k,c) items over 256 threads
    int c = t & 15, kk = t >> 4;
#pragma unroll
    for (int rep = 0; rep < 2; ++rep) {
        int k = kk + 16 * rep;
        int nb = (int)sel[k];
        const float* Xr = X + (size_t)nb * FDIM;
        float acc = bg[c];
#pragma unroll
        for (int f = 0; f < FDIM; ++f) acc = fmaf(Xr[f], Wg[f * 16 + c], acc);
        acc = fmaf(y[nb], Wg[FDIM * 16 + c], acc);
        gkc[k * 16 + c] = tanhf(acc);
    }
    __syncthreads();
    if (t < 16) {
        float s = 0.f;
#pragma unroll
        for (int k = 0; k < KNN; ++k) s += gkc[k * 16 + t];
        aggc[t] = s;
    }
    __syncthreads();
    if (t < 128) {
        const float* xq = x + (size_t)q * FDIM;
        float acc = b1[t];
#pragma unroll
        for (int f = 0; f < FDIM; ++f) acc = fmaf(xq[f], W1[f * 128 + t], acc);
#pragma unroll
        for (int cc = 0; cc < 16; ++cc) acc = fmaf(aggc[cc], W1[(FDIM + cc) * 128 + t], acc);
        red[t] = tanhf(acc) * Wl[t];
    }
    __syncthreads();
    for (int off = 64; off > 0; off >>= 1) {
        if (t < off) red[t] += red[t + off];
        __syncthreads();
    }
    if (t == 0) out[q] = 1.f / (1.f + expf(-(red[0] + bl[0])));
}

extern "C" void kernel_launch(void* const* d_in, const int* in_sizes, int n_in,
                              void* d_out, int out_size, void* d_ws, size_t ws_size,
                              hipStream_t stream) {
    const float* x  = (const float*)d_in[0];
    const float* X  = (const float*)d_in[1];
    const float* y  = (const float*)d_in[2];
    const float* Wg = (const float*)d_in[3];
    const float* bg = (const float*)d_in[4];
    const float* W1 = (const float*)d_in[5];
    const float* b1 = (const float*)d_in[6];
    const float* Wl = (const float*)d_in[7];
    const float* bl = (const float*)d_in[8];
    float* out = (float*)d_out;

    int B = in_sizes[0] / FDIM;  // 1024
    int N = in_sizes[1] / FDIM;  // 200000

    char* w = (char*)d_ws;
    size_t off = 0;
    float* Xn = (float*)(w + off); off += (size_t)N * 4;            off = (off + 255) & ~(size_t)255;
    float* Tq = (float*)(w + off); off += (size_t)B * 4;            off = (off + 255) & ~(size_t)255;
    u32* hist = (u32*)(w + off);   size_t histB = (size_t)B * 512;  off += histB; off = (off + 255) & ~(size_t)255;
    u32* cnt  = (u32*)(w + off);   off += (size_t)B * 4;            off = (off + 255) & ~(size_t)255;
    u64* list = (u64*)(w + off);

    // candidate capacity: expected ~600/query; shrink if ws is tight
    int cap = MAXCAP;
    size_t avail = (ws_size > off) ? (ws_size - off) : 0;
    size_t capFit = avail / ((size_t)B * 8);
    if (capFit < (size_t)cap) cap = (int)capFit;
    if (cap < 64) cap = 64;  // degenerate-ws fallback; still runs

    hipMemsetAsync(hist, 0, histB, stream);
    hipMemsetAsync(cnt, 0, (size_t)B * 4, stream);

    k_xnorm<<<dim3((N + 255) / 256), 256, 0, stream>>>(X, Xn, N);

    int nsamp = (N + 15) / 16;           // stride-16 sample
    int sj = (nsamp + 15) / 16;          // samples per histogram chunk-block
    k_hist<<<dim3(B / 256, 16), 256, 0, stream>>>(x, X, Xn, hist, N, nsamp, sj);
    k_thresh<<<dim3((B + 255) / 256), 256, 0, stream>>>(hist, Tq, B);
    k_filter<<<dim3(B / 256, (N + 1023) / 1024), 256, 0, stream>>>(x, X, Xn, Tq, cnt, list, N, cap);
    k_final<<<dim3(B), 256, 0, stream>>>(x, X, y, Wg, bg, W1, b1, Wl, bl, cnt, list, out, cap);
}

// Round 2
// 941.002 us; speedup vs baseline: 1.6468x; 1.6468x over previous
//
#include <hip/hip_runtime.h>
#include <cstdint>

#define FDIM 64
#define KNN 32
#define NBUCKET 256
#define MAXCAP2 4096
#define TM 128
#define TN 128
#define PADK 72   // 64 bf16 + 8 pad (16B) -> conflict-free b128 frag reads/writes

typedef unsigned int u32;
typedef unsigned long long u64;
typedef __attribute__((ext_vector_type(8))) short bf16x8;
typedef __attribute__((ext_vector_type(4))) float f32x4;

// ---- shared fp32 helpers: identical FMA DAG everywhere exact d2 is computed
__device__ __forceinline__ float load_query(const float* __restrict__ x, int q, float4* xv) {
    const float4* xp = (const float4*)(x + (size_t)q * FDIM);
    float n0 = 0.f, n1 = 0.f, n2 = 0.f, n3 = 0.f;
#pragma unroll
    for (int k = 0; k < 16; ++k) {
        float4 v = xp[k];
        xv[k] = v;
        n0 = fmaf(v.x, v.x, n0); n1 = fmaf(v.y, v.y, n1);
        n2 = fmaf(v.z, v.z, n2); n3 = fmaf(v.w, v.w, n3);
    }
    return (n0 + n1) + (n2 + n3);
}

__device__ __forceinline__ float dot_row(const float4* __restrict__ xv, const float* __restrict__ row) {
    const float4* rv = (const float4*)row;
    float d0 = 0.f, d1 = 0.f, d2 = 0.f, d3 = 0.f;
#pragma unroll
    for (int k = 0; k < 16; ++k) {
        float4 r = rv[k];
        float4 a = xv[k];
        d0 = fmaf(a.x, r.x, d0); d1 = fmaf(a.y, r.y, d1);
        d2 = fmaf(a.z, r.z, d2); d3 = fmaf(a.w, r.w, d3);
    }
    return (d0 + d1) + (d2 + d3);
}

// ---- K1: row norms (used for X -> Xn and x -> qn)
__global__ __launch_bounds__(256) void k_xnorm(const float* __restrict__ X, float* __restrict__ Xn, int N) {
    int i = blockIdx.x * 256 + threadIdx.x;
    if (i >= N) return;
    const float4* r = (const float4*)(X + (size_t)i * FDIM);
    float d0 = 0.f, d1 = 0.f, d2 = 0.f, d3 = 0.f;
#pragma unroll
    for (int k = 0; k < 16; ++k) {
        float4 v = r[k];
        d0 = fmaf(v.x, v.x, d0); d1 = fmaf(v.y, v.y, d1);
        d2 = fmaf(v.z, v.z, d2); d3 = fmaf(v.w, v.w, d3);
    }
    Xn[i] = (d0 + d1) + (d2 + d3);
}

// ---- K1b: fp32 -> bf16 (RNE), 8 elems/thread
__global__ __launch_bounds__(256) void k_cvt(const float* __restrict__ src, ushort* __restrict__ dst, int n8) {
    int i = blockIdx.x * 256 + threadIdx.x;
    if (i >= n8) return;
    const float4* s = (const float4*)src + 2 * (size_t)i;
    float4 a = s[0], b = s[1];
    ushort o[8];
    const float* f = &a.x;
#pragma unroll
    for (int k = 0; k < 4; ++k) {
        u32 u = __float_as_uint(f[k]);
        o[k] = (ushort)((u + 0x7fffu + ((u >> 16) & 1u)) >> 16);
    }
    const float* g = &b.x;
#pragma unroll
    for (int k = 0; k < 4; ++k) {
        u32 u = __float_as_uint(g[k]);
        o[4 + k] = (ushort)((u + 0x7fffu + ((u >> 16) & 1u)) >> 16);
    }
    *(uint4*)(dst + 8 * (size_t)i) = *(uint4*)o;
}

// ---- K2: per-query histogram of exact d2 over stride-16 sample
__global__ __launch_bounds__(256) void k_hist(const float* __restrict__ x, const float* __restrict__ X,
                                              const float* __restrict__ Xn, u32* __restrict__ hist,
                                              int N, int nsamp, int sj) {
    __shared__ unsigned char h8[NBUCKET * 256];
    int t = threadIdx.x;
    u32* h32 = (u32*)h8;
#pragma unroll
    for (int k = 0; k < 64; ++k) h32[k * 256 + t] = 0;
    __syncthreads();

    int q = blockIdx.x * 256 + t;
    float4 xv[16];
    float xn = load_query(x, q, xv);

    for (int j = 0; j < sj; ++j) {
        int s = blockIdx.y * sj + j;
        int p = s * 16;
        if (s < nsamp && p < N) {
            float dp = dot_row(xv, X + (size_t)p * FDIM);
            float d2 = fmaxf(xn + Xn[p] - 2.f * dp, 0.f);
            int b = min(NBUCKET - 1, (int)d2);
            int idx = b * 256 + t;
            unsigned char v = h8[idx];
            h8[idx] = (v == 255u) ? v : (unsigned char)(v + 1);
        }
    }
    __syncthreads();
#pragma unroll
    for (int w = 0; w < 128; ++w) {
        u32 v0 = h8[(2 * w) * 256 + t];
        u32 v1 = h8[(2 * w + 1) * 256 + t];
        if (v0 | v1) atomicAdd(&hist[(size_t)q * 128 + w], v0 | (v1 << 16));
    }
}

// ---- K2b: Tf = (upper edge of first bucket with cum >= 32) + margin for bf16 error
__global__ __launch_bounds__(256) void k_thresh(const u32* __restrict__ hist, float* __restrict__ Tq, int B) {
    int q = blockIdx.x * 256 + threadIdx.x;
    if (q >= B) return;
    const u32* h = hist + (size_t)q * 128;
    int cum = 0;
    float T = (float)NBUCKET;
    for (int w = 0; w < 128; ++w) {
        u32 v = h[w];
        cum += (int)(v & 0xffffu);
        if (cum >= KNN) { T = (float)(2 * w + 1); break; }
        cum += (int)(v >> 16);
        if (cum >= KNN) { T = (float)(2 * w + 2); break; }
    }
    Tq[q] = T + 2.0f;  // margin >> |bf16 dot error| keeps a superset of true top-32
}

// ---- K3 (MFMA): 128x128 tile of d2_approx = qn + Xn - 2*(xb @ Xb^T); append p if < Tf
__global__ __launch_bounds__(256) void k_mfma_filter(const ushort* __restrict__ xb, const ushort* __restrict__ Xb,
                                                     const float* __restrict__ qn, const float* __restrict__ Xn,
                                                     const float* __restrict__ Tf,
                                                     u32* __restrict__ cnt, u32* __restrict__ list,
                                                     int N, int cap) {
    __shared__ alignas(16) ushort As[TM * PADK];
    __shared__ alignas(16) ushort Bs[TN * PADK];
    __shared__ float XnS[TN];
    __shared__ float qnS[TM];
    __shared__ float TfS[TM];

    int t = threadIdx.x;
    int qbase = blockIdx.x * TM;
    int pbase = blockIdx.y * TN;

    {   // stage A: 128 rows x 128B, wave covers 1KB contiguous per instr
        const uint4* g = (const uint4*)(xb + (size_t)qbase * FDIM);
        int row4 = t >> 3, ch = t & 7;
#pragma unroll
        for (int rnd = 0; rnd < 4; ++rnd) {
            int row = rnd * 32 + row4;
            uint4 v = g[row * 8 + ch];
            *(uint4*)&As[row * PADK + ch * 8] = v;
        }
        // stage B with row clamp (epilogue guards p < N)
        int Nm1 = N - 1;
#pragma unroll
        for (int rnd = 0; rnd < 4; ++rnd) {
            int row = rnd * 32 + row4;
            int pc = min(pbase + row, Nm1);
            uint4 v = *(const uint4*)(Xb + (size_t)pc * FDIM + ch * 8);
            *(uint4*)&Bs[row * PADK + ch * 8] = v;
        }
    }
    if (t < TN) XnS[t] = Xn[min(pbase + t, N - 1)];
    if (t < TM) { qnS[t] = qn[qbase + t]; TfS[t] = Tf[qbase + t]; }
    __syncthreads();

    int w = t >> 6, L = t & 63, G = L >> 4, r = L & 15;
    f32x4 acc[2][8];
#pragma unroll
    for (int mi = 0; mi < 2; ++mi)
#pragma unroll
        for (int ni = 0; ni < 8; ++ni) acc[mi][ni] = (f32x4){0.f, 0.f, 0.f, 0.f};

#pragma unroll
    for (int kk = 0; kk < 2; ++kk) {
        int ko = kk * 32 + G * 8;
        bf16x8 a0 = *(bf16x8*)&As[(w * 32 + r) * PADK + ko];
        bf16x8 a1 = *(bf16x8*)&As[(w * 32 + 16 + r) * PADK + ko];
#pragma unroll
        for (int ni = 0; ni < 8; ++ni) {
            bf16x8 b = *(bf16x8*)&Bs[(ni * 16 + r) * PADK + ko];
            acc[0][ni] = __builtin_amdgcn_mfma_f32_16x16x32_bf16(a0, b, acc[0][ni], 0, 0, 0);
            acc[1][ni] = __builtin_amdgcn_mfma_f32_16x16x32_bf16(a1, b, acc[1][ni], 0, 0, 0);
        }
    }

    // C layout (m89): col = lane&15, row = (lane>>4)*4 + reg
#pragma unroll
    for (int mi = 0; mi < 2; ++mi) {
        int rl0 = w * 32 + mi * 16 + G * 4;
#pragma unroll
        for (int ni = 0; ni < 8; ++ni) {
            int pl = ni * 16 + r;
            int p = pbase + pl;
            float xnp = XnS[pl];
#pragma unroll
            for (int reg = 0; reg < 4; ++reg) {
                int rl = rl0 + reg;
                float d2 = qnS[rl] + xnp - 2.f * acc[mi][ni][reg];
                if (d2 < TfS[rl] && p < N) {
                    int q = qbase + rl;
                    u32 slot = atomicAdd(&cnt[q], 1u);
                    if (slot < (u32)cap) list[(size_t)q * cap + slot] = (u32)p;
                }
            }
        }
    }
}

// ---- K3 (scalar fallback, used only if ws can't fit the bf16 copy of X)
__global__ __launch_bounds__(256) void k_filter_scalar(const float* __restrict__ x, const float* __restrict__ X,
                                                       const float* __restrict__ Xn, const float* __restrict__ Tq,
                                                       u32* __restrict__ cnt, u32* __restrict__ list,
                                                       int N, int cap) {
    int t = threadIdx.x;
    int q = blockIdx.x * 256 + t;
    float4 xv[16];
    float xn = load_query(x, q, xv);
    float T = Tq[q];
    int base = blockIdx.y * 1024;
    int lim = min(1024, N - base);
    for (int j = 0; j < lim; ++j) {
        int p = base + j;
        float dp = dot_row(xv, X + (size_t)p * FDIM);
        float d2 = fmaxf(xn + Xn[p] - 2.f * dp, 0.f);
        if (d2 < T) {
            u32 slot = atomicAdd(&cnt[q], 1u);
            if (slot < (u32)cap) list[(size_t)q * cap + slot] = (u32)p;
        }
    }
}

// ---- K4: exact fp32 rescore of candidates, exact top-32 (tie-break low idx), NN head
__global__ __launch_bounds__(256) void k_final(const float* __restrict__ x, const float* __restrict__ X,
                                               const float* __restrict__ y, const float* __restrict__ Xn,
                                               const float* __restrict__ Wg, const float* __restrict__ bg,
                                               const float* __restrict__ W1, const float* __restrict__ b1,
                                               const float* __restrict__ Wl, const float* __restrict__ bl,
                                               const u32* __restrict__ cnt, const u32* __restrict__ list,
                                               float* __restrict__ out, int cap) {
    __shared__ u64 keys[MAXCAP2];
    __shared__ u64 wk[4];
    __shared__ int wp[4];
    __shared__ u32 sel[KNN];
    __shared__ float gkc[KNN * 16];
    __shared__ float aggc[16];
    __shared__ float red[128];

    int t = threadIdx.x;
    int q = blockIdx.x;
    int m = (int)min(cnt[q], (u32)cap);

    float4 xv[16];
    float xn = load_query(x, q, xv);

    const u32* lq = list + (size_t)q * cap;
    for (int i = t; i < m; i += 256) {
        u32 p = lq[i];
        float dp = dot_row(xv, X + (size_t)p * FDIM);
        float d2 = fmaxf(xn + Xn[p] - 2.f * dp, 0.f);
        keys[i] = ((u64)__float_as_uint(d2) << 32) | p;
    }
    __syncthreads();

    for (int r = 0; r < KNN; ++r) {
        u64 bk = ~0ull;
        int bp = -1;
        for (int i = t; i < m; i += 256) {
            u64 k = keys[i];
            if (k < bk) { bk = k; bp = i; }
        }
#pragma unroll
        for (int off = 32; off > 0; off >>= 1) {
            u64 ok = __shfl_down(bk, off);
            int op = __shfl_down(bp, off);
            if (ok < bk) { bk = ok; bp = op; }
        }
        if ((t & 63) == 0) { wk[t >> 6] = bk; wp[t >> 6] = bp; }
        __syncthreads();
        if (t == 0) {
            u64 fb = wk[0];
            int fp = wp[0];
            for (int w = 1; w < 4; ++w)
                if (wk[w] < fb) { fb = wk[w]; fp = wp[w]; }
            sel[r] = (u32)(fb & 0xffffffffu);
            if (fp >= 0) keys[fp] = ~0ull;
        }
        __syncthreads();
    }

    int c = t & 15, kk = t >> 4;
#pragma unroll
    for (int rep = 0; rep < 2; ++rep) {
        int k = kk + 16 * rep;
        int nb = (int)sel[k];
        const float* Xr = X + (size_t)nb * FDIM;
        float acc = bg[c];
#pragma unroll
        for (int f = 0; f < FDIM; ++f) acc = fmaf(Xr[f], Wg[f * 16 + c], acc);
        acc = fmaf(y[nb], Wg[FDIM * 16 + c], acc);
        gkc[k * 16 + c] = tanhf(acc);
    }
    __syncthreads();
    if (t < 16) {
        float s = 0.f;
#pragma unroll
        for (int k = 0; k < KNN; ++k) s += gkc[k * 16 + t];
        aggc[t] = s;
    }
    __syncthreads();
    if (t < 128) {
        const float* xq = x + (size_t)q * FDIM;
        float acc = b1[t];
#pragma unroll
        for (int f = 0; f < FDIM; ++f) acc = fmaf(xq[f], W1[f * 128 + t], acc);
#pragma unroll
        for (int cc = 0; cc < 16; ++cc) acc = fmaf(aggc[cc], W1[(FDIM + cc) * 128 + t], acc);
        red[t] = tanhf(acc) * Wl[t];
    }
    __syncthreads();
    for (int off = 64; off > 0; off >>= 1) {
        if (t < off) red[t] += red[t + off];
        __syncthreads();
    }
    if (t == 0) out[q] = 1.f / (1.f + expf(-(red[0] + bl[0])));
}

extern "C" void kernel_launch(void* const* d_in, const int* in_sizes, int n_in,
                              void* d_out, int out_size, void* d_ws, size_t ws_size,
                              hipStream_t stream) {
    const float* x  = (const float*)d_in[0];
    const float* X  = (const float*)d_in[1];
    const float* y  = (const float*)d_in[2];
    const float* Wg = (const float*)d_in[3];
    const float* bg = (const float*)d_in[4];
    const float* W1 = (const float*)d_in[5];
    const float* b1 = (const float*)d_in[6];
    const float* Wl = (const float*)d_in[7];
    const float* bl = (const float*)d_in[8];
    float* out = (float*)d_out;

    int B = in_sizes[0] / FDIM;  // 1024
    int N = in_sizes[1] / FDIM;  // 200000

    char* w = (char*)d_ws;
    size_t off = 0;
    auto alloc = [&](size_t bytes) { void* p = w + off; off += (bytes + 255) & ~(size_t)255; return p; };
    float* Xn  = (float*)alloc((size_t)N * 4);
    float* qn  = (float*)alloc((size_t)B * 4);
    u32* hist  = (u32*)alloc((size_t)B * 512);
    float* Tq  = (float*)alloc((size_t)B * 4);
    u32* cnt   = (u32*)alloc((size_t)B * 4);

    size_t xbB = (size_t)B * FDIM * 2;
    size_t XbB = (size_t)N * FDIM * 2;
    size_t rem = (ws_size > off) ? ws_size - off : 0;
    bool mfma_path = rem >= xbB + XbB + 512 + (size_t)B * 2048 * 4;

    ushort* xb = nullptr; ushort* Xb = nullptr;
    int cap;
    if (mfma_path) {
        xb = (ushort*)alloc(xbB);
        Xb = (ushort*)alloc(XbB);
        rem = ws_size - off;
        size_t c = rem / ((size_t)B * 4);
        cap = c > MAXCAP2 ? MAXCAP2 : (int)c;
    } else {
        size_t c = rem / ((size_t)B * 4);
        cap = c > MAXCAP2 ? MAXCAP2 : (int)c;
        if (cap < 64) cap = 64;
    }
    u32* list = (u32*)alloc((size_t)B * cap * 4);

    hipMemsetAsync(hist, 0, (size_t)B * 512, stream);
    hipMemsetAsync(cnt, 0, (size_t)B * 4, stream);

    k_xnorm<<<dim3((N + 255) / 256), 256, 0, stream>>>(X, Xn, N);
    k_xnorm<<<dim3((B + 255) / 256), 256, 0, stream>>>(x, qn, B);

    int nsamp = (N + 15) / 16;
    int chunks = 64;
    int sj = (nsamp + chunks - 1) / chunks;
    k_hist<<<dim3(B / 256, chunks), 256, 0, stream>>>(x, X, Xn, hist, N, nsamp, sj);
    k_thresh<<<dim3((B + 255) / 256), 256, 0, stream>>>(hist, Tq, B);

    if (mfma_path) {
        int nx8 = B * FDIM / 8, nX8 = N * FDIM / 8;
        k_cvt<<<dim3((nx8 + 255) / 256), 256, 0, stream>>>(x, xb, nx8);
        k_cvt<<<dim3((nX8 + 255) / 256), 256, 0, stream>>>(X, Xb, nX8);
        k_mfma_filter<<<dim3(B / TM, (N + TN - 1) / TN), 256, 0, stream>>>(
            xb, Xb, qn, Xn, Tq, cnt, list, N, cap);
    } else {
        k_filter_scalar<<<dim3(B / 256, (N + 1023) / 1024), 256, 0, stream>>>(
            x, X, Xn, Tq, cnt, list, N, cap);
    }

    k_final<<<dim3(B), 256, 0, stream>>>(x, X, y, Xn, Wg, bg, W1, b1, Wl, bl, cnt, list, out, cap);
}